// Round 4
// baseline (747.029 us; speedup 1.0000x reference)
//
#include <hip/hip_runtime.h>
#include <stdint.h>

#define M_DIM 8192
#define N_DIM 11008
#define K_DIM 4096

#define BM 256
#define BN 256
#define BK 64
#define NT (K_DIM / BK)          // 64 K-tiles
#define GRID_M (M_DIM / BM)      // 32
#define GRID_N (N_DIM / BN)      // 43
#define NWG (GRID_M * GRID_N)    // 1376 (divisible by 8 -> simple XCD swizzle OK)

#define BUF_ELEMS (BM * BK)      // 16384 u16 = 32 KiB per buffer

typedef unsigned short u16;
typedef short short8 __attribute__((ext_vector_type(8)));
typedef float f32x4 __attribute__((ext_vector_type(4)));
typedef u16 u16x8 __attribute__((ext_vector_type(8)));

// ---------- helpers ----------

__device__ __forceinline__ u16 f2bf_rne(float f) {
    uint32_t u = __float_as_uint(f);
    u += 0x7FFFu + ((u >> 16) & 1u);   // round-to-nearest-even
    return (u16)(u >> 16);
}

__device__ __forceinline__ u16 signbf(float f) {
    if (f == 0.0f) return 0;
    return (u16)(0x3F80u | ((__float_as_uint(f) >> 16) & 0x8000u)); // ±1.0 bf16
}

__device__ __forceinline__ f32x4 MFMA(short8 a, short8 b, f32x4 c) {
    return __builtin_amdgcn_mfma_f32_16x16x32_bf16(a, b, c, 0, 0, 0);
}

#define GLOAD16(src, dst)                                                              \
    __builtin_amdgcn_global_load_lds(                                                  \
        (const __attribute__((address_space(1))) uint32_t*)(src),                      \
        (__attribute__((address_space(3))) uint32_t*)(dst), 16, 0, 0)

// ---------- pre-pass: f32 x -> bf16 ----------

__global__ void convert_x_kernel(const float* __restrict__ x, u16* __restrict__ xb, long long n) {
    long long i = ((long long)blockIdx.x * blockDim.x + threadIdx.x) * 8;
    long long stride = (long long)gridDim.x * blockDim.x * 8;
    for (; i < n; i += stride) {
        float4 f0 = *(const float4*)(x + i);
        float4 f1 = *(const float4*)(x + i + 4);
        u16x8 r;
        r[0] = f2bf_rne(f0.x); r[1] = f2bf_rne(f0.y);
        r[2] = f2bf_rne(f0.z); r[3] = f2bf_rne(f0.w);
        r[4] = f2bf_rne(f1.x); r[5] = f2bf_rne(f1.y);
        r[6] = f2bf_rne(f1.z); r[7] = f2bf_rne(f1.w);
        *(u16x8*)(xb + i) = r;
    }
}

// ---------- pre-pass: f32 w -> sign(w) in bf16 (exact {-1,0,+1}) ----------

__global__ void convert_w_kernel(const float* __restrict__ w, u16* __restrict__ wb, long long n) {
    long long i = ((long long)blockIdx.x * blockDim.x + threadIdx.x) * 8;
    long long stride = (long long)gridDim.x * blockDim.x * 8;
    for (; i < n; i += stride) {
        float4 f0 = *(const float4*)(w + i);
        float4 f1 = *(const float4*)(w + i + 4);
        u16x8 r;
        r[0] = signbf(f0.x); r[1] = signbf(f0.y);
        r[2] = signbf(f0.z); r[3] = signbf(f0.w);
        r[4] = signbf(f1.x); r[5] = signbf(f1.y);
        r[6] = signbf(f1.z); r[7] = signbf(f1.w);
        *(u16x8*)(wb + i) = r;
    }
}

// ---------- main GEMM: 256x256 tile, BK=64, 8 waves, register-pipelined
// 2-phase K-loop, 1 barrier per K-tile, XOR-swizzled LDS ----------
//
// Per wave (wm,wn of 2x4): owns A rows m*32+wm*16+[0,16) m=0..7, B rows
// n*64+wn*16+[0,16) n=0..3 -> acc[8][4] fragments.
//
// Phase A(t): issue 12 ds_reads of (t,kk=1) frags -> set1; MFMA 32 on set0;
//             vmcnt(0)  [per-wave: stage(t+1), issued at B(t-1), landed]
//             lgkmcnt(0); s_barrier
//             *** vmcnt BEFORE barrier: after the barrier, ALL waves' stage
//             loads for tile t+1 have landed (vmcnt is per-wave; a barrier
//             alone does NOT drain other waves' async gload_lds). ***
// Phase B(t): issue 12 ds_reads of (t+1,kk=0) -> set0 from buf[(t+1)&1];
//             issue 8 global_load_lds stage(t+2) -> buf[t&1];
//             MFMA 32 on set1.
//
// Hazards: RAW stage(t+1)->reads guarded by A(t)-end vmcnt(0)+barrier (all
// waves). WAR reads(buf[t&1])->stage(t+2) guarded by A(t)-end lgkmcnt(0)
// (drains each wave's B(t-1) kk0 + A(t) kk1 reads) + barrier; stage issues
// after. Register sets a0/b0/a1/b1 alternate per phase (within-wave order).

__global__ __launch_bounds__(512, 2) void ternary_gemm_256(
    const u16* __restrict__ A, const u16* __restrict__ B,
    const float* __restrict__ bias, float* __restrict__ out)
{
    extern __shared__ u16 lds[];
    u16* As = lds;                    // [2][BUF_ELEMS]
    u16* Bs = lds + 2 * BUF_ELEMS;    // [2][BUF_ELEMS]

    const int tid  = threadIdx.x;
    const int lane = tid & 63;
    const int wid  = tid >> 6;        // 0..7
    const int wm   = wid >> 2;        // 0..1
    const int wn   = wid & 3;         // 0..3
    const int l15  = lane & 15;
    const int l4   = lane >> 4;       // 0..3
    const int p7   = lane & 7;

    // T1: bijective XCD swizzle (NWG % 8 == 0), bn-minor for A-panel L2 reuse
    const int bid = blockIdx.x;
    const int swz = (bid & 7) * (NWG / 8) + (bid >> 3);
    const int bm  = swz / GRID_N;
    const int bn  = swz % GRID_N;
    const long brow = (long)bm * BM;
    const long bcol = (long)bn * BN;

    // ---- staging addressing (per-thread constant) ----
    const int rowt = tid >> 3;                       // 0..63
    const int sx   = (tid & 7) ^ (rowt & 7);         // inverse-swizzled source slot
    const u16* pA = A + (size_t)(brow + rowt) * K_DIM + sx * 8;
    const u16* pB = B + (size_t)(bcol + rowt) * K_DIM + sx * 8;

    // stage one half (h=0 rows 0-127, h=1 rows 128-255) of tile t: 2 insts
    auto stage = [&](const u16* base, u16* ldsmat, int t, int h) {
        const int b = t & 1;
        #pragma unroll
        for (int rr = 0; rr < 2; ++rr) {
            const int r = h * 2 + rr;
            GLOAD16(base + (size_t)r * (64 * K_DIM) + (size_t)t * BK,
                    ldsmat + b * BUF_ELEMS + r * 4096 + wid * 512);
        }
    };

    // ---- fragment read addressing (swizzled: slot ^= row&7) ----
    const int slot0 = l4 ^ p7;          // kk=0 16B-slot
    const int slot1 = slot0 ^ 4;        // kk=1
    const int aBase = (wm * 16 + l15) * 64;
    const int bBase = (wn * 16 + l15) * 64;

    auto rdA = [&](int b, int mg, int kk) -> short8 {
        return *(const short8*)&As[b * BUF_ELEMS + aBase + mg * 2048 + (kk ? slot1 : slot0) * 8];
    };
    auto rdB = [&](int b, int ng, int kk) -> short8 {
        return *(const short8*)&Bs[b * BUF_ELEMS + bBase + ng * 4096 + (kk ? slot1 : slot0) * 8];
    };

    f32x4 acc[8][4];
    #pragma unroll
    for (int m = 0; m < 8; ++m)
        #pragma unroll
        for (int n = 0; n < 4; ++n) acc[m][n] = (f32x4){0.f, 0.f, 0.f, 0.f};

    // ---- prologue: stage tiles 0 and 1 (16 insts); wait tile 0 (vmcnt THEN
    // barrier -> all waves' tile-0 loads landed); preload set0 ----
    stage(pA, As, 0, 0); stage(pA, As, 0, 1);
    stage(pB, Bs, 0, 0); stage(pB, Bs, 0, 1);
    stage(pA, As, 1, 0); stage(pA, As, 1, 1);
    stage(pB, Bs, 1, 0); stage(pB, Bs, 1, 1);
    asm volatile("s_waitcnt vmcnt(8)" ::: "memory");
    __builtin_amdgcn_s_barrier();
    __builtin_amdgcn_sched_barrier(0);

    short8 a0[8], b0[4], a1[8], b1[4];
    #pragma unroll
    for (int m = 0; m < 8; ++m) a0[m] = rdA(0, m, 0);
    #pragma unroll
    for (int n = 0; n < 4; ++n) b0[n] = rdB(0, n, 0);

    for (int t = 0; t < NT; ++t) {
        const int b = t & 1;

        // ======== phase A: read (t,kk1)->set1 ; MFMA set0 ; tile boundary ========
        #pragma unroll
        for (int m = 0; m < 8; ++m) a1[m] = rdA(b, m, 1);
        #pragma unroll
        for (int n = 0; n < 4; ++n) b1[n] = rdB(b, n, 1);
        __builtin_amdgcn_sched_barrier(0);
        __builtin_amdgcn_s_setprio(1);
        #pragma unroll
        for (int m = 0; m < 8; ++m)
            #pragma unroll
            for (int n = 0; n < 4; ++n)
                acc[m][n] = MFMA(a0[m], b0[n], acc[m][n]);
        __builtin_amdgcn_s_setprio(0);
        __builtin_amdgcn_sched_barrier(0);
        asm volatile("s_waitcnt vmcnt(0)" ::: "memory");   // own stage(t+1) landed
        asm volatile("s_waitcnt lgkmcnt(0)" ::: "memory"); // own reads of buf[t&1] done
        __builtin_amdgcn_s_barrier();                      // => ALL waves' both
        __builtin_amdgcn_sched_barrier(0);

        // ======== phase B: read (t+1,kk0)->set0 ; stage(t+2) ; MFMA set1 ========
        if (t + 1 < NT) {
            const int b2 = (t + 1) & 1;
            #pragma unroll
            for (int m = 0; m < 8; ++m) a0[m] = rdA(b2, m, 0);
            #pragma unroll
            for (int n = 0; n < 4; ++n) b0[n] = rdB(b2, n, 0);
        }
        if (t + 2 < NT) {
            stage(pA, As, t + 2, 0); stage(pA, As, t + 2, 1);
            stage(pB, Bs, t + 2, 0); stage(pB, Bs, t + 2, 1);
        }
        __builtin_amdgcn_sched_barrier(0);
        __builtin_amdgcn_s_setprio(1);
        #pragma unroll
        for (int m = 0; m < 8; ++m)
            #pragma unroll
            for (int n = 0; n < 4; ++n)
                acc[m][n] = MFMA(a1[m], b1[n], acc[m][n]);
        __builtin_amdgcn_s_setprio(0);
        __builtin_amdgcn_sched_barrier(0);
    }

    // ---- epilogue: C/D layout col=lane&15, row=(lane>>4)*4+reg (m89-verified) ----
    #pragma unroll
    for (int n = 0; n < 4; ++n) {
        const int col = (int)bcol + n * 64 + wn * 16 + l15;
        const float bv = bias[col];
        #pragma unroll
        for (int m = 0; m < 8; ++m) {
            const size_t row0 = (size_t)brow + m * 32 + wm * 16 + l4 * 4;
            #pragma unroll
            for (int r = 0; r < 4; ++r)
                out[(row0 + r) * N_DIM + col] = acc[m][n][r] + bv;
        }
    }
}

// ---------- fallback (only if workspace too small): correct but slow ----------

__global__ void naive_kernel(const float* __restrict__ x, const float* __restrict__ w,
                             const float* __restrict__ bias, float* __restrict__ out) {
    long long o = (long long)blockIdx.x * blockDim.x + threadIdx.x;
    if (o >= (long long)M_DIM * N_DIM) return;
    int row = (int)(o / N_DIM), col = (int)(o % N_DIM);
    float s = 0.0f;
    const float* xr = x + (size_t)row * K_DIM;
    const float* wr = w + (size_t)col * K_DIM;
    for (int k = 0; k < K_DIM; ++k) {
        float wv = wr[k];
        s += (wv > 0.0f) ? xr[k] : ((wv < 0.0f) ? -xr[k] : 0.0f);
    }
    out[o] = s + bias[col];
}

// ---------- launch ----------

extern "C" void kernel_launch(void* const* d_in, const int* in_sizes, int n_in,
                              void* d_out, int out_size, void* d_ws, size_t ws_size,
                              hipStream_t stream) {
    const float* x    = (const float*)d_in[0];
    const float* w    = (const float*)d_in[1];
    const float* bias = (const float*)d_in[2];
    float* out        = (float*)d_out;

    const size_t xb_bytes = (size_t)M_DIM * K_DIM * sizeof(u16);  // 64 MiB
    const size_t wb_bytes = (size_t)N_DIM * K_DIM * sizeof(u16);  // 86 MiB

    if (ws_size >= xb_bytes + wb_bytes) {
        u16* xb = (u16*)d_ws;
        u16* wb = (u16*)((char*)d_ws + xb_bytes);

        const long long nx = (long long)M_DIM * K_DIM;
        const long long nw = (long long)N_DIM * K_DIM;
        convert_x_kernel<<<(int)(nx / (256 * 8)), 256, 0, stream>>>(x, xb, nx);
        convert_w_kernel<<<(int)(nw / (256 * 8)), 256, 0, stream>>>(w, wb, nw);

        hipFuncSetAttribute(reinterpret_cast<const void*>(ternary_gemm_256),
                            hipFuncAttributeMaxDynamicSharedMemorySize, 131072);
        ternary_gemm_256<<<NWG, 512, 131072, stream>>>(xb, wb, bias, out);
    } else {
        const long long total = (long long)M_DIM * N_DIM;
        naive_kernel<<<(int)((total + 255) / 256), 256, 0, stream>>>(x, w, bias, out);
    }
}